// Round 3
// baseline (5085.075 us; speedup 1.0000x reference)
//
#include <hip/hip_runtime.h>
#include <hip/hip_fp16.h>

#define T_TOK 256
#define NNODE 2049
#define HENC  256
#define DHID  512
#define DIN   800
#define G4    1024
#define DG4   2048

typedef _Float16 f16;
typedef _Float16 f16x2 __attribute__((ext_vector_type(2)));
typedef short    bf16x8 __attribute__((ext_vector_type(8)));
typedef float    f32x4  __attribute__((ext_vector_type(4)));

static __device__ __forceinline__ float sigm(float x){ return 1.0f/(1.0f+__expf(-x)); }
static __device__ __forceinline__ float tanhfast(float x){ return 1.0f - 2.0f/(__expf(2.0f*x)+1.0f); }

static __device__ __forceinline__ unsigned short f2bf(float x){
    unsigned u = __builtin_bit_cast(unsigned, x);
    unsigned r = (u + 0x7fffu + ((u>>16)&1u)) >> 16;
    return (unsigned short)r;
}
static __device__ __forceinline__ unsigned packh2(float a, float b){
    f16 ha = (f16)a, hb = (f16)b;
    unsigned short ua = __builtin_bit_cast(unsigned short, ha);
    unsigned short ub = __builtin_bit_cast(unsigned short, hb);
    return (unsigned)ua | ((unsigned)ub << 16);
}
static __device__ __forceinline__ float fdot2(unsigned wpk, unsigned hpk, float c){
#if __has_builtin(__builtin_amdgcn_fdot2)
    return __builtin_amdgcn_fdot2(__builtin_bit_cast(f16x2, wpk),
                                  __builtin_bit_cast(f16x2, hpk), c, false);
#else
    float d;
    asm volatile("v_dot2_f32_f16 %0, %1, %2, %3" : "=v"(d) : "v"(wpk), "v"(hpk), "v"(c));
    return d;
#endif
}

// ---------------- embedding gather -> bf16 ----------------
__global__ void k_embed(const int* __restrict__ lat,
                        const float* __restrict__ form, const float* __restrict__ lemma,
                        const float* __restrict__ tag,  const float* __restrict__ feats,
                        unsigned short* __restrict__ embB){
    int n = blockIdx.x;
    const int* L = lat + n*11;
    int i0 = L[0], i1 = L[1], i2 = L[2];
    for (int c = threadIdx.x; c < DIN; c += blockDim.x){
        float v;
        if (c < 300)      v = form[i0*300 + c];
        else if (c < 600) v = lemma[i1*300 + (c-300)];
        else if (c < 700) v = tag[i2*100 + (c-600)];
        else {
            float s = 0.f;
            #pragma unroll
            for (int j=0;j<6;++j) s += feats[L[3+j]*100 + (c-700)];
            v = s * (1.0f/6.0f);
        }
        embB[n*DIN + c] = f2bf(v);
    }
}

__global__ void k_f32_to_bf16(const float* __restrict__ src, unsigned short* __restrict__ dst, int n){
    int i = blockIdx.x*blockDim.x + threadIdx.x;
    if (i < n) dst[i] = f2bf(src[i]);
}

// pack Whh for scan v3: block b=(d,p) thread t owns rows {q*256+p*128+j : q=0..3},
// j = (t>>6)*16 + (t&15), col chunk cq = (t&63)>>4 (cols cq*64 .. cq*64+63).
// wreg[(b*128 + q*32 + m)*512 + t] = packh2(W[row][cq*64+2m], W[row][cq*64+2m+1])
__global__ void k_pack_whh_v3(const float* __restrict__ wf, const float* __restrict__ wb,
                              unsigned* __restrict__ wreg){
    int id = blockIdx.x*blockDim.x + threadIdx.x;
    if (id >= 2048) return;
    int b = id >> 9, t = id & 511;
    int d = b >> 1, p = b & 1;
    const float* W = d ? wb : wf;
    int l = t & 63, w = t >> 6;
    int cq = l >> 4, j = w*16 + (l & 15);
    for (int q=0;q<4;++q){
        int row = q*256 + p*128 + j;
        const float* R = W + (size_t)row*256 + cq*64;
        for (int m=0;m<32;++m){
            wreg[((size_t)(b*128 + q*32 + m))*512 + t] = packh2(R[2*m], R[2*m+1]);
        }
    }
}

// ---------------- bf16 MFMA GEMM: C[M][Nc] = A[M][K] * B[Nc][K]^T (+bias) ----------------
__global__ __launch_bounds__(256) void k_gemm_bf16(const unsigned short* __restrict__ A,
                                                   const unsigned short* __restrict__ B,
                                                   float* __restrict__ C,
                                                   const float* __restrict__ bias,
                                                   int M, int Nc, int K){
    __shared__ unsigned short As[64][40];
    __shared__ unsigned short Bs[64][40];
    int m0 = blockIdx.x*64, n0 = blockIdx.y*64;
    int t = threadIdx.x, w = t>>6, lane = t&63;
    f32x4 acc[4];
    #pragma unroll
    for (int i=0;i<4;++i) acc[i] = (f32x4){0.f,0.f,0.f,0.f};
    int rowl = t>>2, kb0 = (t&3)*8;
    for (int k0=0; k0<K; k0+=32){
        uint4 av;
        int ar = m0 + rowl;
        if (ar < M) av = *(const uint4*)(A + (size_t)ar*K + k0 + kb0);
        else { av.x=av.y=av.z=av.w=0u; }
        *(uint4*)&As[rowl][kb0] = av;
        *(uint4*)&Bs[rowl][kb0] = *(const uint4*)(B + (size_t)(n0+rowl)*K + k0 + kb0);
        __syncthreads();
        int arow = w*16 + (lane&15), kk = (lane>>4)*8;
        bf16x8 af = *(const bf16x8*)&As[arow][kk];
        #pragma unroll
        for (int nt=0;nt<4;++nt){
            bf16x8 bf = *(const bf16x8*)&Bs[nt*16 + (lane&15)][kk];
            acc[nt] = __builtin_amdgcn_mfma_f32_16x16x32_bf16(af, bf, acc[nt], 0,0,0);
        }
        __syncthreads();
    }
    #pragma unroll
    for (int nt=0;nt<4;++nt){
        int col = n0 + nt*16 + (lane&15);
        float bb = bias ? bias[col] : 0.0f;
        #pragma unroll
        for (int r=0;r<4;++r){
            int row = m0 + w*16 + (lane>>4)*4 + r;
            if (row < M) C[(size_t)row*Nc + col] = acc[nt][r] + bb;
        }
    }
}

// ---------------- sequential bi-LSTM scan v3: 4 blocks (dir x half), all weights in VGPRs --
// Block b: d=b>>1, p=b&1. Owns units p*128..p*128+127 of direction d (all 4 gates).
// Cross-block per-step exchange of 128 h values via agent-scope atomics.
__global__ __launch_bounds__(512, 1) void k_lstm_scan(const unsigned* __restrict__ wreg,
                                                      const float* __restrict__ XgF,
                                                      const float* __restrict__ XgB,
                                                      int* __restrict__ flg,
                                                      float* __restrict__ xh,
                                                      float* __restrict__ encoded,
                                                      float* __restrict__ h0,
                                                      float* __restrict__ c0){
    __shared__ uint4 sH4[32];          // 256 h as f16 (512 B)
    __shared__ float sG[512];
    int b = blockIdx.x;
    int d = b >> 1, p = b & 1, pb = d*2 + (1-p);
    int t = threadIdx.x;
    int l = t & 63, w = t >> 6;
    int cq = l >> 4, j = w*16 + (l & 15);
    const float* Xg = d ? XgB : XgF;
    unsigned* sH32 = (unsigned*)sH4;
    f16* sHh = (f16*)sH4;

    unsigned wv[128];
    #pragma unroll
    for (int k=0;k<128;++k) wv[k] = wreg[((size_t)(b*128 + k))*512 + t];
    if (t < 128) sH32[t] = 0u;
    float c_reg = 0.0f;
    __syncthreads();

    int node  = d ? (NNODE-1) : 0;
    int stepd = d ? -1 : 1;

    for (int s=0; s<NNODE; ++s){
        // prefetch per-row input gates (writer lanes only)
        float xg0=0.f,xg1=0.f,xg2=0.f,xg3=0.f;
        if (cq == 0){
            const float* xr = Xg + (size_t)node*G4 + p*128 + j;
            xg0 = xr[0]; xg1 = xr[256]; xg2 = xr[512]; xg3 = xr[768];
        }
        float a0=0.f,a1=0.f,a2=0.f,a3=0.f;
        #pragma unroll
        for (int m4=0;m4<8;++m4){
            uint4 hv = sH4[cq*8 + m4];
            a0 = fdot2(wv[0*32+m4*4+0], hv.x, a0);
            a0 = fdot2(wv[0*32+m4*4+1], hv.y, a0);
            a0 = fdot2(wv[0*32+m4*4+2], hv.z, a0);
            a0 = fdot2(wv[0*32+m4*4+3], hv.w, a0);
            a1 = fdot2(wv[1*32+m4*4+0], hv.x, a1);
            a1 = fdot2(wv[1*32+m4*4+1], hv.y, a1);
            a1 = fdot2(wv[1*32+m4*4+2], hv.z, a1);
            a1 = fdot2(wv[1*32+m4*4+3], hv.w, a1);
            a2 = fdot2(wv[2*32+m4*4+0], hv.x, a2);
            a2 = fdot2(wv[2*32+m4*4+1], hv.y, a2);
            a2 = fdot2(wv[2*32+m4*4+2], hv.z, a2);
            a2 = fdot2(wv[2*32+m4*4+3], hv.w, a2);
            a3 = fdot2(wv[3*32+m4*4+0], hv.x, a3);
            a3 = fdot2(wv[3*32+m4*4+1], hv.y, a3);
            a3 = fdot2(wv[3*32+m4*4+2], hv.z, a3);
            a3 = fdot2(wv[3*32+m4*4+3], hv.w, a3);
        }
        a0 += __shfl_xor(a0,16); a0 += __shfl_xor(a0,32);
        a1 += __shfl_xor(a1,16); a1 += __shfl_xor(a1,32);
        a2 += __shfl_xor(a2,16); a2 += __shfl_xor(a2,32);
        a3 += __shfl_xor(a3,16); a3 += __shfl_xor(a3,32);
        if (cq == 0){
            sG[0*128 + j] = a0 + xg0;
            sG[1*128 + j] = a1 + xg1;
            sG[2*128 + j] = a2 + xg2;
            sG[3*128 + j] = a3 + xg3;
        }
        __syncthreads();                               // A: sG ready
        if (t < 128){
            float gi = sG[t], gf = sG[128+t], gg = sG[256+t], go = sG[384+t];
            float c = sigm(gf)*c_reg + sigm(gi)*tanhfast(gg);
            c_reg = c;
            float h = sigm(go)*tanhfast(c);
            __hip_atomic_store(&xh[((b*2) + (s&1))*128 + t], h,
                               __ATOMIC_RELAXED, __HIP_MEMORY_SCOPE_AGENT);
            sHh[p*128 + t] = (f16)h;
            encoded[(size_t)node*DHID + d*HENC + p*128 + t] = h;
            if (s == NNODE-1){ h0[d*HENC + p*128 + t] = h; c0[d*HENC + p*128 + t] = c; }
        }
        __syncthreads();                               // B: drains xh stores (vmcnt0)
        if (t == 0){
            __hip_atomic_store(&flg[b], s+1, __ATOMIC_RELEASE, __HIP_MEMORY_SCOPE_AGENT);
            int iters = 0;
            while (__hip_atomic_load(&flg[pb], __ATOMIC_ACQUIRE, __HIP_MEMORY_SCOPE_AGENT) < s+1){
                if (++iters > (1<<26)) break;          // safety valve vs. hang
            }
        }
        __syncthreads();                               // C: partner data visible
        if (t < 128){
            float hp = __hip_atomic_load(&xh[((pb*2) + (s&1))*128 + t],
                                         __ATOMIC_RELAXED, __HIP_MEMORY_SCOPE_AGENT);
            sHh[(1-p)*128 + t] = (f16)hp;
        }
        __syncthreads();                               // D: full h ready for next step
        node += stepd;
    }
}

// Kd = dec_whh @ h0 + dec_b
__global__ void k_dec_const(const float* __restrict__ dec_whh, const float* __restrict__ dec_b,
                            const float* __restrict__ h0, float* __restrict__ Kd){
    __shared__ float sh[512];
    int t = threadIdx.x;
    int r = blockIdx.x*256 + t;
    sh[t] = h0[t]; sh[256+t] = h0[256+t];
    __syncthreads();
    float a = 0.f;
    const float* Wr = dec_whh + (size_t)r*512;
    for (int k=0;k<512;++k) a += Wr[k]*sh[k];
    Kd[r] = a + dec_b[r];
}

// decoder h for every possible ptr node
__global__ void k_hall(const float* __restrict__ G, const float* __restrict__ Kd,
                       const float* __restrict__ c0, float* __restrict__ Hall){
    int n = blockIdx.x, u = threadIdx.x;
    const float* g = G + (size_t)n*DG4;
    float gi = g[u]        + Kd[u];
    float gf = g[512+u]    + Kd[512+u];
    float gg = g[1024+u]   + Kd[1024+u];
    float go = g[1536+u]   + Kd[1536+u];
    float c  = sigm(gf)*c0[u] + sigm(gi)*tanhfast(gg);
    Hall[(size_t)n*DHID + u] = sigm(go)*tanhfast(c);
}

// S[i][p][c] = encoded[cand(i,c)] . Hall[prev(i,p)]
__global__ __launch_bounds__(256) void k_scores(const float* __restrict__ encoded,
                                                const float* __restrict__ Hall,
                                                float* __restrict__ S){
    __shared__ float sE[8][512];
    __shared__ float sHp[8][512];
    int i = blockIdx.x, t = threadIdx.x;
    for (int idx = t; idx < 8*512; idx += 256){
        int r = idx >> 9, c = idx & 511;
        int cand = 1 + i*8 + r;
        sE[r][c] = encoded[(size_t)cand*DHID + c];
        int prev = (i==0) ? 0 : (1 + (i-1)*8 + r);
        sHp[r][c] = Hall[(size_t)prev*DHID + c];
    }
    __syncthreads();
    int w = t>>6, lane = t&63;
    for (int q=0;q<16;++q){
        int pi = w*16 + q, p = pi>>3, c = pi&7;
        float v = 0.f;
        #pragma unroll
        for (int j=0;j<8;++j) v += sE[c][lane*8+j]*sHp[p][lane*8+j];
        #pragma unroll
        for (int off=32; off; off>>=1) v += __shfl_xor(v, off);
        if (lane==0) S[i*64 + p*8 + c] = v;
    }
}

// sequential pointer chain + loss
__global__ __launch_bounds__(256) void k_decode(const float* __restrict__ S, float* __restrict__ out){
    __shared__ float nll[2048];
    __shared__ int   cst[2048];
    __shared__ int   path[256];
    __shared__ float wsum[4];
    int t = threadIdx.x;
    for (int p=0;p<8;++p){
        const float* s = S + t*64 + p*8;
        float m = s[0]; int am = 0;
        #pragma unroll
        for (int c=1;c<8;++c){ float v = s[c]; if (v > m){ m = v; am = c; } }
        float e = 0.f;
        #pragma unroll
        for (int c=0;c<8;++c) e += __expf(s[c]-m);
        float lse = m + __logf(e);
        nll[t*8+p] = lse - s[0];
        cst[t*8+p] = am;
    }
    __syncthreads();
    if (t == 0){
        int p = 0;
        for (int i=0;i<256;++i){
            int idx = i*8 + p;
            path[i] = idx;
            int c = cst[idx];
            out[i+1] = (float)(1 + i*8 + c);
            p = c;
        }
        out[0] = 0.0f;
    }
    __syncthreads();
    float v = nll[path[t]];
    #pragma unroll
    for (int off=32; off; off>>=1) v += __shfl_xor(v, off);
    if ((t&63)==0) wsum[t>>6] = v;
    __syncthreads();
    if (t==0) out[257] = (wsum[0]+wsum[1]+wsum[2]+wsum[3]) * (1.0f/256.0f);
}

extern "C" void kernel_launch(void* const* d_in, const int* in_sizes, int n_in,
                              void* d_out, int out_size, void* d_ws, size_t ws_size,
                              hipStream_t stream){
    (void)in_sizes; (void)n_in; (void)out_size; (void)ws_size;
    const int*   lattice  = (const int*)  d_in[0];
    const float* form     = (const float*)d_in[2];
    const float* lemma    = (const float*)d_in[3];
    const float* tag      = (const float*)d_in[4];
    const float* feats    = (const float*)d_in[5];
    const float* wih_f    = (const float*)d_in[6];
    const float* whh_f    = (const float*)d_in[7];
    const float* b_f      = (const float*)d_in[8];
    const float* wih_b    = (const float*)d_in[9];
    const float* whh_b    = (const float*)d_in[10];
    const float* b_b      = (const float*)d_in[11];
    const float* dwih     = (const float*)d_in[12];
    const float* dwhh     = (const float*)d_in[13];
    const float* db       = (const float*)d_in[14];
    float* out = (float*)d_out;

    char* ws = (char*)d_ws;
    size_t o = 0;
    auto alloc = [&](size_t bytes)->char*{ char* p = ws + o; o = (o + bytes + 255) & ~(size_t)255; return p; };
    int*            flg    = (int*)alloc(256);                      // 4 flags
    float*          xh     = (float*)alloc(4096);                   // [4][2][128] f32
    unsigned short* embB   = (unsigned short*)alloc((size_t)NNODE*DIN*2);
    unsigned short* wihfB  = (unsigned short*)alloc((size_t)G4*DIN*2);
    unsigned short* wihbB  = (unsigned short*)alloc((size_t)G4*DIN*2);
    unsigned short* dwihB  = (unsigned short*)alloc((size_t)DG4*DIN*2);
    unsigned*       wreg   = (unsigned*)alloc((size_t)4*128*512*4);
    float*          XgF    = (float*)alloc((size_t)NNODE*G4*4);
    float*          XgB    = (float*)alloc((size_t)NNODE*G4*4);
    float*          Graw   = (float*)alloc((size_t)NNODE*DG4*4);
    float*          enc    = (float*)alloc((size_t)NNODE*DHID*4);
    float*          h0     = (float*)alloc(512*4);
    float*          c0     = (float*)alloc(512*4);
    float*          Kd     = (float*)alloc(2048*4);
    float*          Hall   = (float*)alloc((size_t)NNODE*DHID*4);
    float*          Sbuf   = (float*)alloc((size_t)256*64*4);

    // reset sync state every launch (graph-capture safe)
    hipMemsetAsync(d_ws, 0, 8192, stream);

    k_f32_to_bf16<<<(G4*DIN+255)/256, 256, 0, stream>>>(wih_f, wihfB, G4*DIN);
    k_f32_to_bf16<<<(G4*DIN+255)/256, 256, 0, stream>>>(wih_b, wihbB, G4*DIN);
    k_f32_to_bf16<<<(DG4*DIN+255)/256, 256, 0, stream>>>(dwih, dwihB, DG4*DIN);
    k_pack_whh_v3<<<8, 256, 0, stream>>>(whh_f, whh_b, wreg);
    k_embed<<<NNODE, 256, 0, stream>>>(lattice, form, lemma, tag, feats, embB);

    dim3 gE((NNODE+63)/64, G4/64);
    k_gemm_bf16<<<gE, 256, 0, stream>>>(embB, wihfB, XgF, b_f, NNODE, G4, DIN);
    k_gemm_bf16<<<gE, 256, 0, stream>>>(embB, wihbB, XgB, b_b, NNODE, G4, DIN);
    dim3 gD((NNODE+63)/64, DG4/64);
    k_gemm_bf16<<<gD, 256, 0, stream>>>(embB, dwihB, Graw, nullptr, NNODE, DG4, DIN);

    k_lstm_scan<<<4, 512, 0, stream>>>(wreg, XgF, XgB, flg, xh, enc, h0, c0);

    k_dec_const<<<8, 256, 0, stream>>>(dwhh, db, h0, Kd);
    k_hall<<<NNODE, 512, 0, stream>>>(Graw, Kd, c0, Hall);
    k_scores<<<256, 256, 0, stream>>>(enc, Hall, Sbuf);
    k_decode<<<1, 256, 0, stream>>>(Sbuf, out);
}

// Round 4
// 4133.628 us; speedup vs baseline: 1.2302x; 1.2302x over previous
//
#include <hip/hip_runtime.h>
#include <hip/hip_fp16.h>

#define T_TOK 256
#define NNODE 2049
#define HENC  256
#define DHID  512
#define DIN   800
#define G4    1024
#define DG4   2048

typedef _Float16 f16;
typedef _Float16 f16x2 __attribute__((ext_vector_type(2)));
typedef short    bf16x8 __attribute__((ext_vector_type(8)));
typedef float    f32x4  __attribute__((ext_vector_type(4)));

static __device__ __forceinline__ float sigm(float x){ return 1.0f/(1.0f+__expf(-x)); }
static __device__ __forceinline__ float tanhfast(float x){ return 1.0f - 2.0f/(__expf(2.0f*x)+1.0f); }

static __device__ __forceinline__ unsigned short f2bf(float x){
    unsigned u = __builtin_bit_cast(unsigned, x);
    unsigned r = (u + 0x7fffu + ((u>>16)&1u)) >> 16;
    return (unsigned short)r;
}
static __device__ __forceinline__ unsigned packh2(float a, float b){
    f16 ha = (f16)a, hb = (f16)b;
    unsigned short ua = __builtin_bit_cast(unsigned short, ha);
    unsigned short ub = __builtin_bit_cast(unsigned short, hb);
    return (unsigned)ua | ((unsigned)ub << 16);
}
static __device__ __forceinline__ float fdot2(unsigned wpk, unsigned hpk, float c){
#if __has_builtin(__builtin_amdgcn_fdot2)
    return __builtin_amdgcn_fdot2(__builtin_bit_cast(f16x2, wpk),
                                  __builtin_bit_cast(f16x2, hpk), c, false);
#else
    float d;
    asm volatile("v_dot2_f32_f16 %0, %1, %2, %3" : "=v"(d) : "v"(wpk), "v"(hpk), "v"(c));
    return d;
#endif
}

// ---------------- embedding gather -> bf16 ----------------
__global__ void k_embed(const int* __restrict__ lat,
                        const float* __restrict__ form, const float* __restrict__ lemma,
                        const float* __restrict__ tag,  const float* __restrict__ feats,
                        unsigned short* __restrict__ embB){
    int n = blockIdx.x;
    const int* L = lat + n*11;
    int i0 = L[0], i1 = L[1], i2 = L[2];
    for (int c = threadIdx.x; c < DIN; c += blockDim.x){
        float v;
        if (c < 300)      v = form[i0*300 + c];
        else if (c < 600) v = lemma[i1*300 + (c-300)];
        else if (c < 700) v = tag[i2*100 + (c-600)];
        else {
            float s = 0.f;
            #pragma unroll
            for (int j=0;j<6;++j) s += feats[L[3+j]*100 + (c-700)];
            v = s * (1.0f/6.0f);
        }
        embB[n*DIN + c] = f2bf(v);
    }
}

__global__ void k_f32_to_bf16(const float* __restrict__ src, unsigned short* __restrict__ dst, int n){
    int i = blockIdx.x*blockDim.x + threadIdx.x;
    if (i < n) dst[i] = f2bf(src[i]);
}

// pack Whh for scan v4: block b=(d,p), thread t: j=(t>>6)*16+(t&15), cq=(t&63)>>4.
// For gate g (0..3), m (0..7): uint4 component c holds f16-pair of
// W[g*256 + p*128 + j][cq*64 + 2*(m*4+c) .. +1]
// stored at wreg4[(b*32 + g*8 + m)*512 + t]
__global__ void k_pack_whh_v4(const float* __restrict__ wf, const float* __restrict__ wb,
                              uint4* __restrict__ wreg4){
    int id = blockIdx.x*blockDim.x + threadIdx.x;
    if (id >= 2048) return;
    int b = id >> 9, t = id & 511;
    int d = b >> 1, p = b & 1;
    const float* W = d ? wb : wf;
    int l = t & 63, w = t >> 6;
    int cq = l >> 4, j = w*16 + (l & 15);
    for (int g=0; g<4; ++g){
        const float* R = W + (size_t)(g*256 + p*128 + j)*256 + cq*64;
        for (int m=0; m<8; ++m){
            uint4 v;
            v.x = packh2(R[2*(m*4+0)], R[2*(m*4+0)+1]);
            v.y = packh2(R[2*(m*4+1)], R[2*(m*4+1)+1]);
            v.z = packh2(R[2*(m*4+2)], R[2*(m*4+2)+1]);
            v.w = packh2(R[2*(m*4+3)], R[2*(m*4+3)+1]);
            wreg4[((size_t)(b*32 + g*8 + m))*512 + t] = v;
        }
    }
}

// ---------------- bf16 MFMA GEMM: C[M][Nc] = A[M][K] * B[Nc][K]^T (+bias) ----------------
__global__ __launch_bounds__(256) void k_gemm_bf16(const unsigned short* __restrict__ A,
                                                   const unsigned short* __restrict__ B,
                                                   float* __restrict__ C,
                                                   const float* __restrict__ bias,
                                                   int M, int Nc, int K){
    __shared__ unsigned short As[64][40];
    __shared__ unsigned short Bs[64][40];
    int m0 = blockIdx.x*64, n0 = blockIdx.y*64;
    int t = threadIdx.x, w = t>>6, lane = t&63;
    f32x4 acc[4];
    #pragma unroll
    for (int i=0;i<4;++i) acc[i] = (f32x4){0.f,0.f,0.f,0.f};
    int rowl = t>>2, kb0 = (t&3)*8;
    for (int k0=0; k0<K; k0+=32){
        uint4 av;
        int ar = m0 + rowl;
        if (ar < M) av = *(const uint4*)(A + (size_t)ar*K + k0 + kb0);
        else { av.x=av.y=av.z=av.w=0u; }
        *(uint4*)&As[rowl][kb0] = av;
        *(uint4*)&Bs[rowl][kb0] = *(const uint4*)(B + (size_t)(n0+rowl)*K + k0 + kb0);
        __syncthreads();
        int arow = w*16 + (lane&15), kk = (lane>>4)*8;
        bf16x8 af = *(const bf16x8*)&As[arow][kk];
        #pragma unroll
        for (int nt=0;nt<4;++nt){
            bf16x8 bf = *(const bf16x8*)&Bs[nt*16 + (lane&15)][kk];
            acc[nt] = __builtin_amdgcn_mfma_f32_16x16x32_bf16(af, bf, acc[nt], 0,0,0);
        }
        __syncthreads();
    }
    #pragma unroll
    for (int nt=0;nt<4;++nt){
        int col = n0 + nt*16 + (lane&15);
        float bb = bias ? bias[col] : 0.0f;
        #pragma unroll
        for (int r=0;r<4;++r){
            int row = m0 + w*16 + (lane>>4)*4 + r;
            if (row < M) C[(size_t)row*Nc + col] = acc[nt][r] + bb;
        }
    }
}

// ---------------- sequential bi-LSTM scan v4: weights in NAMED uint4 registers ----------
#define LOADW(g,m) const uint4 W##g##_##m = wreg4[((size_t)(b*32 + g*8 + m))*512 + t];

#define STEPM(m) { uint4 hv = sH4[cq*8 + m]; \
    a0 = fdot2(W0_##m.x, hv.x, a0); a0 = fdot2(W0_##m.y, hv.y, a0); \
    a0 = fdot2(W0_##m.z, hv.z, a0); a0 = fdot2(W0_##m.w, hv.w, a0); \
    a1 = fdot2(W1_##m.x, hv.x, a1); a1 = fdot2(W1_##m.y, hv.y, a1); \
    a1 = fdot2(W1_##m.z, hv.z, a1); a1 = fdot2(W1_##m.w, hv.w, a1); \
    a2 = fdot2(W2_##m.x, hv.x, a2); a2 = fdot2(W2_##m.y, hv.y, a2); \
    a2 = fdot2(W2_##m.z, hv.z, a2); a2 = fdot2(W2_##m.w, hv.w, a2); \
    a3 = fdot2(W3_##m.x, hv.x, a3); a3 = fdot2(W3_##m.y, hv.y, a3); \
    a3 = fdot2(W3_##m.z, hv.z, a3); a3 = fdot2(W3_##m.w, hv.w, a3); }

__global__ __launch_bounds__(512, 2) void k_lstm_scan(const uint4* __restrict__ wreg4,
                                                      const float* __restrict__ XgF,
                                                      const float* __restrict__ XgB,
                                                      int* __restrict__ flg,
                                                      float* __restrict__ xh,
                                                      float* __restrict__ encoded,
                                                      float* __restrict__ h0,
                                                      float* __restrict__ c0){
    __shared__ uint4 sH4[32];          // 256 h as f16 (512 B)
    __shared__ float sG[512];
    int b = blockIdx.x;
    int d = b >> 1, p = b & 1, pb = d*2 + (1-p);
    int t = threadIdx.x;
    int l = t & 63, w = t >> 6;
    int cq = l >> 4, j = w*16 + (l & 15);
    const float* Xg = d ? XgB : XgF;
    unsigned* sH32 = (unsigned*)sH4;
    f16* sHh = (f16*)sH4;

    LOADW(0,0) LOADW(0,1) LOADW(0,2) LOADW(0,3) LOADW(0,4) LOADW(0,5) LOADW(0,6) LOADW(0,7)
    LOADW(1,0) LOADW(1,1) LOADW(1,2) LOADW(1,3) LOADW(1,4) LOADW(1,5) LOADW(1,6) LOADW(1,7)
    LOADW(2,0) LOADW(2,1) LOADW(2,2) LOADW(2,3) LOADW(2,4) LOADW(2,5) LOADW(2,6) LOADW(2,7)
    LOADW(3,0) LOADW(3,1) LOADW(3,2) LOADW(3,3) LOADW(3,4) LOADW(3,5) LOADW(3,6) LOADW(3,7)

    if (t < 128) sH32[t] = 0u;
    float c_reg = 0.0f;
    __syncthreads();

    int node  = d ? (NNODE-1) : 0;
    int stepd = d ? -1 : 1;

    for (int s=0; s<NNODE; ++s){
        // prefetch per-row input gates (writer lanes only)
        float xg0=0.f,xg1=0.f,xg2=0.f,xg3=0.f;
        if (cq == 0){
            const float* xr = Xg + (size_t)node*G4 + p*128 + j;
            xg0 = xr[0]; xg1 = xr[256]; xg2 = xr[512]; xg3 = xr[768];
        }
        float a0=0.f,a1=0.f,a2=0.f,a3=0.f;
        STEPM(0) STEPM(1) STEPM(2) STEPM(3) STEPM(4) STEPM(5) STEPM(6) STEPM(7)
        a0 += __shfl_xor(a0,16); a0 += __shfl_xor(a0,32);
        a1 += __shfl_xor(a1,16); a1 += __shfl_xor(a1,32);
        a2 += __shfl_xor(a2,16); a2 += __shfl_xor(a2,32);
        a3 += __shfl_xor(a3,16); a3 += __shfl_xor(a3,32);
        if (cq == 0){
            sG[0*128 + j] = a0 + xg0;
            sG[1*128 + j] = a1 + xg1;
            sG[2*128 + j] = a2 + xg2;
            sG[3*128 + j] = a3 + xg3;
        }
        __syncthreads();                               // A: sG ready
        if (t < 128){
            float gi = sG[t], gf = sG[128+t], gg = sG[256+t], go = sG[384+t];
            float c = sigm(gf)*c_reg + sigm(gi)*tanhfast(gg);
            c_reg = c;
            float h = sigm(go)*tanhfast(c);
            __hip_atomic_store(&xh[((b*2) + (s&1))*128 + t], h,
                               __ATOMIC_RELAXED, __HIP_MEMORY_SCOPE_AGENT);
            sHh[p*128 + t] = (f16)h;
            encoded[(size_t)node*DHID + d*HENC + p*128 + t] = h;
            if (s == NNODE-1){ h0[d*HENC + p*128 + t] = h; c0[d*HENC + p*128 + t] = c; }
        }
        __syncthreads();                               // B: drains xh stores
        if (t == 0){
            __hip_atomic_store(&flg[b], s+1, __ATOMIC_RELEASE, __HIP_MEMORY_SCOPE_AGENT);
            int iters = 0;
            while (__hip_atomic_load(&flg[pb], __ATOMIC_ACQUIRE, __HIP_MEMORY_SCOPE_AGENT) < s+1){
                if (++iters > (1<<26)) break;          // safety valve vs. hang
            }
        }
        __syncthreads();                               // C: partner data visible
        if (t < 128){
            float hp = __hip_atomic_load(&xh[((pb*2) + (s&1))*128 + t],
                                         __ATOMIC_RELAXED, __HIP_MEMORY_SCOPE_AGENT);
            sHh[(1-p)*128 + t] = (f16)hp;
        }
        __syncthreads();                               // D: full h ready for next step
        node += stepd;
    }
}

// Kd = dec_whh @ h0 + dec_b
__global__ void k_dec_const(const float* __restrict__ dec_whh, const float* __restrict__ dec_b,
                            const float* __restrict__ h0, float* __restrict__ Kd){
    __shared__ float sh[512];
    int t = threadIdx.x;
    int r = blockIdx.x*256 + t;
    sh[t] = h0[t]; sh[256+t] = h0[256+t];
    __syncthreads();
    float a = 0.f;
    const float* Wr = dec_whh + (size_t)r*512;
    for (int k=0;k<512;++k) a += Wr[k]*sh[k];
    Kd[r] = a + dec_b[r];
}

// decoder h for every possible ptr node
__global__ void k_hall(const float* __restrict__ G, const float* __restrict__ Kd,
                       const float* __restrict__ c0, float* __restrict__ Hall){
    int n = blockIdx.x, u = threadIdx.x;
    const float* g = G + (size_t)n*DG4;
    float gi = g[u]        + Kd[u];
    float gf = g[512+u]    + Kd[512+u];
    float gg = g[1024+u]   + Kd[1024+u];
    float go = g[1536+u]   + Kd[1536+u];
    float c  = sigm(gf)*c0[u] + sigm(gi)*tanhfast(gg);
    Hall[(size_t)n*DHID + u] = sigm(go)*tanhfast(c);
}

// S[i][p][c] = encoded[cand(i,c)] . Hall[prev(i,p)]
__global__ __launch_bounds__(256) void k_scores(const float* __restrict__ encoded,
                                                const float* __restrict__ Hall,
                                                float* __restrict__ S){
    __shared__ float sE[8][512];
    __shared__ float sHp[8][512];
    int i = blockIdx.x, t = threadIdx.x;
    for (int idx = t; idx < 8*512; idx += 256){
        int r = idx >> 9, c = idx & 511;
        int cand = 1 + i*8 + r;
        sE[r][c] = encoded[(size_t)cand*DHID + c];
        int prev = (i==0) ? 0 : (1 + (i-1)*8 + r);
        sHp[r][c] = Hall[(size_t)prev*DHID + c];
    }
    __syncthreads();
    int w = t>>6, lane = t&63;
    for (int q=0;q<16;++q){
        int pi = w*16 + q, p = pi>>3, c = pi&7;
        float v = 0.f;
        #pragma unroll
        for (int j=0;j<8;++j) v += sE[c][lane*8+j]*sHp[p][lane*8+j];
        #pragma unroll
        for (int off=32; off; off>>=1) v += __shfl_xor(v, off);
        if (lane==0) S[i*64 + p*8 + c] = v;
    }
}

// sequential pointer chain + loss
__global__ __launch_bounds__(256) void k_decode(const float* __restrict__ S, float* __restrict__ out){
    __shared__ float nll[2048];
    __shared__ int   cst[2048];
    __shared__ int   path[256];
    __shared__ float wsum[4];
    int t = threadIdx.x;
    for (int p=0;p<8;++p){
        const float* s = S + t*64 + p*8;
        float m = s[0]; int am = 0;
        #pragma unroll
        for (int c=1;c<8;++c){ float v = s[c]; if (v > m){ m = v; am = c; } }
        float e = 0.f;
        #pragma unroll
        for (int c=0;c<8;++c) e += __expf(s[c]-m);
        float lse = m + __logf(e);
        nll[t*8+p] = lse - s[0];
        cst[t*8+p] = am;
    }
    __syncthreads();
    if (t == 0){
        int p = 0;
        for (int i=0;i<256;++i){
            int idx = i*8 + p;
            path[i] = idx;
            int c = cst[idx];
            out[i+1] = (float)(1 + i*8 + c);
            p = c;
        }
        out[0] = 0.0f;
    }
    __syncthreads();
    float v = nll[path[t]];
    #pragma unroll
    for (int off=32; off; off>>=1) v += __shfl_xor(v, off);
    if ((t&63)==0) wsum[t>>6] = v;
    __syncthreads();
    if (t==0) out[257] = (wsum[0]+wsum[1]+wsum[2]+wsum[3]) * (1.0f/256.0f);
}

extern "C" void kernel_launch(void* const* d_in, const int* in_sizes, int n_in,
                              void* d_out, int out_size, void* d_ws, size_t ws_size,
                              hipStream_t stream){
    (void)in_sizes; (void)n_in; (void)out_size; (void)ws_size;
    const int*   lattice  = (const int*)  d_in[0];
    const float* form     = (const float*)d_in[2];
    const float* lemma    = (const float*)d_in[3];
    const float* tag      = (const float*)d_in[4];
    const float* feats    = (const float*)d_in[5];
    const float* wih_f    = (const float*)d_in[6];
    const float* whh_f    = (const float*)d_in[7];
    const float* b_f      = (const float*)d_in[8];
    const float* wih_b    = (const float*)d_in[9];
    const float* whh_b    = (const float*)d_in[10];
    const float* b_b      = (const float*)d_in[11];
    const float* dwih     = (const float*)d_in[12];
    const float* dwhh     = (const float*)d_in[13];
    const float* db       = (const float*)d_in[14];
    float* out = (float*)d_out;

    char* ws = (char*)d_ws;
    size_t o = 0;
    auto alloc = [&](size_t bytes)->char*{ char* p = ws + o; o = (o + bytes + 255) & ~(size_t)255; return p; };
    int*            flg    = (int*)alloc(256);                      // 4 flags
    float*          xh     = (float*)alloc(4096);                   // [4][2][128] f32
    unsigned short* embB   = (unsigned short*)alloc((size_t)NNODE*DIN*2);
    unsigned short* wihfB  = (unsigned short*)alloc((size_t)G4*DIN*2);
    unsigned short* wihbB  = (unsigned short*)alloc((size_t)G4*DIN*2);
    unsigned short* dwihB  = (unsigned short*)alloc((size_t)DG4*DIN*2);
    uint4*          wreg4  = (uint4*)alloc((size_t)4*32*512*16);
    float*          XgF    = (float*)alloc((size_t)NNODE*G4*4);
    float*          XgB    = (float*)alloc((size_t)NNODE*G4*4);
    float*          Graw   = (float*)alloc((size_t)NNODE*DG4*4);
    float*          enc    = (float*)alloc((size_t)NNODE*DHID*4);
    float*          h0     = (float*)alloc(512*4);
    float*          c0     = (float*)alloc(512*4);
    float*          Kd     = (float*)alloc(2048*4);
    float*          Hall   = (float*)alloc((size_t)NNODE*DHID*4);
    float*          Sbuf   = (float*)alloc((size_t)256*64*4);

    // reset sync state every launch (graph-capture safe)
    hipMemsetAsync(d_ws, 0, 8192, stream);

    k_f32_to_bf16<<<(G4*DIN+255)/256, 256, 0, stream>>>(wih_f, wihfB, G4*DIN);
    k_f32_to_bf16<<<(G4*DIN+255)/256, 256, 0, stream>>>(wih_b, wihbB, G4*DIN);
    k_f32_to_bf16<<<(DG4*DIN+255)/256, 256, 0, stream>>>(dwih, dwihB, DG4*DIN);
    k_pack_whh_v4<<<8, 256, 0, stream>>>(whh_f, whh_b, wreg4);
    k_embed<<<NNODE, 256, 0, stream>>>(lattice, form, lemma, tag, feats, embB);

    dim3 gE((NNODE+63)/64, G4/64);
    k_gemm_bf16<<<gE, 256, 0, stream>>>(embB, wihfB, XgF, b_f, NNODE, G4, DIN);
    k_gemm_bf16<<<gE, 256, 0, stream>>>(embB, wihbB, XgB, b_b, NNODE, G4, DIN);
    dim3 gD((NNODE+63)/64, DG4/64);
    k_gemm_bf16<<<gD, 256, 0, stream>>>(embB, dwihB, Graw, nullptr, NNODE, DG4, DIN);

    k_lstm_scan<<<4, 512, 0, stream>>>(wreg4, XgF, XgB, flg, xh, enc, h0, c0);

    k_dec_const<<<8, 256, 0, stream>>>(dwhh, db, h0, Kd);
    k_hall<<<NNODE, 512, 0, stream>>>(Graw, Kd, c0, Hall);
    k_scores<<<256, 256, 0, stream>>>(enc, Hall, Sbuf);
    k_decode<<<1, 256, 0, stream>>>(Sbuf, out);
}